// Round 1
// 173.514 us; speedup vs baseline: 1.0051x; 1.0051x over previous
//
#include <hip/hip_runtime.h>
#include <math.h>

#define NB 32
#define LL 512
#define HH 1024
#define H2 512
#define DA 64

typedef unsigned int u32;
typedef unsigned short u16;
typedef __bf16 bf16x8 __attribute__((ext_vector_type(8)));
typedef float f32x4 __attribute__((ext_vector_type(4)));

__device__ __forceinline__ u16 f2bu(float f) {          // fp32 -> bf16 bits, RNE
    u32 u = __builtin_bit_cast(u32, f);
    u = (u + 0x7fff + ((u >> 16) & 1)) >> 16;
    return (u16)u;
}

__device__ __forceinline__ float b2f(u16 u) {           // bf16 bits -> fp32
    u32 v = (u32)u << 16;
    return __builtin_bit_cast(float, v);
}

__device__ __forceinline__ void async_cp16(const void* g, void* l) {
    __builtin_amdgcn_global_load_lds(
        (const __attribute__((address_space(1))) u32*)g,
        (__attribute__((address_space(3))) u32*)l, 16, 0, 0);
}

// ========== prep: bf16 weight materialization (tiny, serial but short) ==========
__global__ void prep_kernel(const float* __restrict__ wv,
                            const float* __restrict__ kqvw,
                            const float* __restrict__ projw,
                            u16* __restrict__ wt, u16* __restrict__ kqvwT,
                            u16* __restrict__ projwT) {
    int e = blockIdx.x * 256 + threadIdx.x;
    if (e < 262144) {
        int m = e >> 9, l = e & 511;
        wt[e] = f2bu(wv[511 + m - l]);
    } else if (e < 262144 + 98304) {
        int i = e - 262144;
        int n = i >> 9, k = i & 511;
        kqvwT[i] = f2bu(kqvw[(size_t)k * 192 + n]);
    } else {
        int i = e - 360448;
        int c = i >> 6, d = i & 63;
        projwT[i] = f2bu(projw[(size_t)d * 512 + c]);
    }
}

// ========== front: LN + transpose + kqv GEMM, 32-row tiles, 512 blocks (2/CU) ==========
// Phase 1 writes raw bf16(v) transposed into T while accumulating LN stats (one x read);
// phase 2 applies the affine from T -> vnT; phase 3 reads A-fragments STRAIGHT FROM T
// (no global re-read, no As staging) with a BK=32 double-buffered B pipeline.
__global__ __launch_bounds__(256, 2)
void front_kernel(const float* __restrict__ x,
                  const float* __restrict__ gamma, const float* __restrict__ beta,
                  const u16* __restrict__ kqvwT, const float* __restrict__ kqvb,
                  u16* __restrict__ vnT,
                  u16* __restrict__ qb, u16* __restrict__ kb, u16* __restrict__ vT) {
    __shared__ u16 Bs[2][192 * 32];             // 2 x 12288 B, double-buffered, swizzled
    __shared__ u16 T[512 * 34];                 // 34816 B: T[c*34+r] = bf16(v[l0+r][c])
    __shared__ float MUs[32], RSs[32];
    int blk = blockIdx.x, t = threadIdx.x;
    int b = blk >> 4, l0 = (blk & 15) * 32;
    int lane = t & 63, wid = t >> 6;
    int l15 = lane & 15, q16 = lane >> 4, q8 = q16 * 8;

    // ---- phase 0: prefetch Bs[0] (k0=0) -- DMA overlaps the LN phase ----
#pragma unroll
    for (int s = 0; s < 3; ++s) {
        int ci = t + s * 256;                   // 768 chunks: 192 rows x 4 slots of 8
        int grow = ci >> 2, gcol = ((ci & 3) ^ (grow & 3)) << 3;
        async_cp16(kqvwT + (size_t)grow * 512 + gcol, &Bs[0][ci * 8]);
    }

    // ---- phase 1: LN stats + raw bf16 transpose write (single x pass) ----
    int r = t >> 3, q = t & 7;                  // r = local row (l), q = 64-col segment
    const float* xr = x + ((size_t)(b * LL + l0 + r)) * HH + H2;
    float s1 = 0.0f, s2 = 0.0f;
#pragma unroll
    for (int i = 0; i < 16; ++i) {
        float4 v = *(const float4*)(xr + q * 64 + i * 4);
        s1 += v.x + v.y + v.z + v.w;
        s2 += v.x * v.x + v.y * v.y + v.z * v.z + v.w * v.w;
        int c = q * 64 + i * 4;
        T[(c + 0) * 34 + r] = f2bu(v.x);
        T[(c + 1) * 34 + r] = f2bu(v.y);
        T[(c + 2) * 34 + r] = f2bu(v.z);
        T[(c + 3) * 34 + r] = f2bu(v.w);
    }
    s1 += __shfl_xor(s1, 1); s2 += __shfl_xor(s2, 1);
    s1 += __shfl_xor(s1, 2); s2 += __shfl_xor(s2, 2);
    s1 += __shfl_xor(s1, 4); s2 += __shfl_xor(s2, 4);
    float mu = s1 * (1.0f / H2);
    float rstd = rsqrtf(s2 * (1.0f / H2) - mu * mu + 1e-5f);
    if ((t & 7) == 0) { MUs[r] = mu; RSs[r] = rstd; }
    __syncthreads();                            // T ready; Bs[0] DMA drained here too

    // ---- phase 2: affine from T -> vnT (no barriers; coalesced 64B lines) ----
    {
        int cc = t >> 2, seg = t & 3;
        float m0 = MUs[seg * 8 + 0], r0s = RSs[seg * 8 + 0];
        float m1 = MUs[seg * 8 + 1], r1s = RSs[seg * 8 + 1];
        float m2 = MUs[seg * 8 + 2], r2s = RSs[seg * 8 + 2];
        float m3 = MUs[seg * 8 + 3], r3s = RSs[seg * 8 + 3];
        float m4 = MUs[seg * 8 + 4], r4s = RSs[seg * 8 + 4];
        float m5 = MUs[seg * 8 + 5], r5s = RSs[seg * 8 + 5];
        float m6 = MUs[seg * 8 + 6], r6s = RSs[seg * 8 + 6];
        float m7 = MUs[seg * 8 + 7], r7s = RSs[seg * 8 + 7];
#pragma unroll
        for (int pass = 0; pass < 8; ++pass) {
            int c = pass * 64 + cc;
            float ga = gamma[c], be = beta[c];
            const u16* Tp = T + c * 34 + seg * 8;
            ushort4 t0 = ((const ushort4*)Tp)[0];
            ushort4 t1 = ((const ushort4*)Tp)[1];
            ushort4 o0, o1;
            o0.x = f2bu((b2f(t0.x) - m0) * r0s * ga + be);
            o0.y = f2bu((b2f(t0.y) - m1) * r1s * ga + be);
            o0.z = f2bu((b2f(t0.z) - m2) * r2s * ga + be);
            o0.w = f2bu((b2f(t0.w) - m3) * r3s * ga + be);
            o1.x = f2bu((b2f(t1.x) - m4) * r4s * ga + be);
            o1.y = f2bu((b2f(t1.y) - m5) * r5s * ga + be);
            o1.z = f2bu((b2f(t1.z) - m6) * r6s * ga + be);
            o1.w = f2bu((b2f(t1.w) - m7) * r7s * ga + be);
            u16* dst = vnT + ((size_t)(b * H2 + c)) * LL + l0 + seg * 8;
            ((ushort4*)dst)[0] = o0;
            ((ushort4*)dst)[1] = o1;
        }
    }

    // ---- phase 3: kqv GEMM, M=32, N=192, BK=32, double-buffered B, A from T ----
    int wm = (wid & 1) * 16, wn = (wid >> 1) * 96;
    int rowA = wm + l15;
    f32x4 acc[6] = {};
    for (int it = 0; it < 16; ++it) {
        if (it < 15) {                          // stage next K-slab into other buffer
            int k0n = (it + 1) * 32, bfn = (it + 1) & 1;
#pragma unroll
            for (int s = 0; s < 3; ++s) {
                int ci = t + s * 256;
                int grow = ci >> 2, gcol = ((ci & 3) ^ (grow & 3)) << 3;
                async_cp16(kqvwT + (size_t)grow * 512 + k0n + gcol, &Bs[bfn][ci * 8]);
            }
        }
        // A fragment straight from T (near-conflict-free: q16 spreads banks by 8)
        bf16x8 a;
        int kb0 = it * 32 + q8;
#pragma unroll
        for (int u = 0; u < 8; ++u)
            a[u] = __builtin_bit_cast(__bf16, T[(kb0 + u) * 34 + rowA]);
        const u16* Bp = &Bs[it & 1][0];
#pragma unroll
        for (int j = 0; j < 6; ++j) {
            int n = wn + j * 16 + l15;
            bf16x8 bb = *(const bf16x8*)(Bp + (n * 4 + (q16 ^ (n & 3))) * 8);
            acc[j] = __builtin_amdgcn_mfma_f32_16x16x32_bf16(a, bb, acc[j], 0, 0, 0);
        }
        __syncthreads();                        // next-buf DMA drained; cur buf released
    }

    // ---- phase 4: epilogue k -> kb, q -> qb, v -> Ts transpose -> vT ----
    u16* Ts = &Bs[0][0];                        // [64][36] = 2304 els, fits in Bs[0]
    int rq = q16 * 4;
#pragma unroll
    for (int rr = 0; rr < 4; ++rr) {
        int mloc = wm + rq + rr;
        size_t mg = (size_t)(b * LL + l0 + mloc);
#pragma unroll
        for (int j = 0; j < 6; ++j) {
            int n = wn + j * 16 + l15;
            u16 hv = f2bu(acc[j][rr] + kqvb[n]);
            if (n < 64)       kb[mg * 64 + n] = hv;
            else if (n < 128) qb[mg * 64 + (n - 64)] = hv;
            else              Ts[(n - 128) * 36 + mloc] = hv;
        }
    }
    __syncthreads();
    int d = t >> 2, lo2 = (t & 3) * 8;
    u16* dst = vT + ((size_t)(b * 64 + d)) * 512 + l0 + lo2;
    const u16* src = Ts + d * 36 + lo2;
    ((ushort4*)dst)[0] = ((const ushort4*)src)[0];
    ((ushort4*)dst)[1] = ((const ushort4*)src)[1];
}

// ========== MFMA flash attention, split-K across 4 waves (unchanged) ==========
#define VLD 136
__global__ __launch_bounds__(256, 4)
void attn_kernel(const u16* __restrict__ qb, const u16* __restrict__ kb,
                 const u16* __restrict__ vT, u16* __restrict__ head) {
    __shared__ u16 Ps[4 * 16 * VLD];
    __shared__ float Osh[4][16 * 65];
    __shared__ float Msh[4][16], Lsh[4][16];
    int b = blockIdx.y, q0 = blockIdx.x * 16;
    int t = threadIdx.x, lane = t & 63, w = t >> 6;
    int l15 = lane & 15, q16 = lane >> 4, q8 = q16 * 8;
    int kc = w * 128;
    const u16* qg = qb + (size_t)b * LL * DA;
    const u16* kg = kb + (size_t)b * LL * DA;
    const u16* vg = vT + (size_t)b * DA * LL;

    bf16x8 aq[2];
#pragma unroll
    for (int s = 0; s < 2; ++s)
        aq[s] = *(const bf16x8*)(qg + (size_t)(q0 + l15) * DA + s * 32 + q8);

    f32x4 sc[8] = {};
#pragma unroll
    for (int j = 0; j < 8; ++j) {
#pragma unroll
        for (int s = 0; s < 2; ++s) {
            bf16x8 bk = *(const bf16x8*)(kg + (size_t)(kc + j * 16 + l15) * DA + s * 32 + q8);
            sc[j] = __builtin_amdgcn_mfma_f32_16x16x32_bf16(aq[s], bk, sc[j], 0, 0, 0);
        }
    }
    float mx[4], sm[4];
#pragma unroll
    for (int j = 0; j < 8; ++j)
#pragma unroll
        for (int rr = 0; rr < 4; ++rr) sc[j][rr] *= 0.125f;
#pragma unroll
    for (int rr = 0; rr < 4; ++rr) {
        float m0 = sc[0][rr];
#pragma unroll
        for (int j = 1; j < 8; ++j) m0 = fmaxf(m0, sc[j][rr]);
        m0 = fmaxf(m0, __shfl_xor(m0, 1));
        m0 = fmaxf(m0, __shfl_xor(m0, 2));
        m0 = fmaxf(m0, __shfl_xor(m0, 4));
        m0 = fmaxf(m0, __shfl_xor(m0, 8));
        mx[rr] = m0;
    }
#pragma unroll
    for (int j = 0; j < 8; ++j)
#pragma unroll
        for (int rr = 0; rr < 4; ++rr) sc[j][rr] = __expf(sc[j][rr] - mx[rr]);
#pragma unroll
    for (int rr = 0; rr < 4; ++rr) {
        float s0 = sc[0][rr];
#pragma unroll
        for (int j = 1; j < 8; ++j) s0 += sc[j][rr];
        s0 += __shfl_xor(s0, 1);
        s0 += __shfl_xor(s0, 2);
        s0 += __shfl_xor(s0, 4);
        s0 += __shfl_xor(s0, 8);
        sm[rr] = s0;
    }
    u16* Pw = Ps + w * 16 * VLD;
#pragma unroll
    for (int j = 0; j < 8; ++j)
#pragma unroll
        for (int rr = 0; rr < 4; ++rr)
            Pw[(q16 * 4 + rr) * VLD + j * 16 + l15] = f2bu(sc[j][rr]);
    f32x4 o[4] = {};
#pragma unroll
    for (int kt = 0; kt < 4; ++kt) {
        bf16x8 ap = *(const bf16x8*)(Pw + l15 * VLD + kt * 32 + q8);
#pragma unroll
        for (int j = 0; j < 4; ++j) {
            bf16x8 bv = *(const bf16x8*)(vg + (size_t)(j * 16 + l15) * LL + kc + kt * 32 + q8);
            o[j] = __builtin_amdgcn_mfma_f32_16x16x32_bf16(ap, bv, o[j], 0, 0, 0);
        }
    }
#pragma unroll
    for (int j = 0; j < 4; ++j)
#pragma unroll
        for (int rr = 0; rr < 4; ++rr)
            Osh[w][(q16 * 4 + rr) * 65 + j * 16 + l15] = o[j][rr];
    if (l15 == 0) {
#pragma unroll
        for (int rr = 0; rr < 4; ++rr) {
            Msh[w][q16 * 4 + rr] = mx[rr];
            Lsh[w][q16 * 4 + rr] = sm[rr];
        }
    }
    __syncthreads();
    int qq = t >> 4, dg = (t & 15) * 4;
    float m0 = Msh[0][qq], m1 = Msh[1][qq], m2 = Msh[2][qq], m3 = Msh[3][qq];
    float ms = fmaxf(fmaxf(m0, m1), fmaxf(m2, m3));
    float f0 = __expf(m0 - ms), f1 = __expf(m1 - ms), f2 = __expf(m2 - ms), f3 = __expf(m3 - ms);
    float lst = Lsh[0][qq] * f0 + Lsh[1][qq] * f1 + Lsh[2][qq] * f2 + Lsh[3][qq] * f3;
    float inv = 1.0f / lst;
    ushort4 res;
    u16* rp = (u16*)&res;
#pragma unroll
    for (int i = 0; i < 4; ++i) {
        int idx = qq * 65 + dg + i;
        float a = Osh[0][idx] * f0 + Osh[1][idx] * f1 + Osh[2][idx] * f2 + Osh[3][idx] * f3;
        rp[i] = f2bu(a * inv);
    }
    *(ushort4*)(head + (size_t)(b * LL + q0 + qq) * DA + dg) = res;
}

// ========== fused Toeplitz GEMM + proj + bias + gate, double-buffered pipeline ==========
__device__ __forceinline__ void mfma_tile64(const u16* As, const u16* Bs,
                                            f32x4 acc[4][4], int wm, int wn,
                                            int l15, int q16) {
    int s7 = l15 & 7;
#pragma unroll
    for (int kk = 0; kk < 2; ++kk) {
        int j0 = kk * 4 + q16;
        bf16x8 a[4], bv[4];
#pragma unroll
        for (int i = 0; i < 4; ++i) {
            int row = wm + i * 16 + l15;
            a[i] = *(const bf16x8*)(As + (row * 8 + (j0 ^ s7)) * 8);
        }
#pragma unroll
        for (int j = 0; j < 4; ++j) {
            int row = wn + j * 16 + l15;
            bv[j] = *(const bf16x8*)(Bs + (row * 8 + (j0 ^ s7)) * 8);
        }
#pragma unroll
        for (int i = 0; i < 4; ++i)
#pragma unroll
            for (int j = 0; j < 4; ++j)
                acc[i][j] = __builtin_amdgcn_mfma_f32_16x16x32_bf16(a[i], bv[j], acc[i][j], 0, 0, 0);
    }
}

__device__ __forceinline__ void stage_pair(const u16* A, const u16* B, int ldk,
                                           int koff, u16* Ad, u16* Bd, int t) {
#pragma unroll
    for (int s = 0; s < 4; ++s) {
        int ci = t + s * 256;
        int grow = ci >> 3, gcol = ((ci & 7) ^ (grow & 7)) << 3;
        async_cp16(A + (size_t)grow * ldk + koff + gcol, Ad + ci * 8);
        async_cp16(B + (size_t)grow * ldk + koff + gcol, Bd + ci * 8);
    }
}

__global__ __launch_bounds__(256, 2)
void mix_kernel(const u16* __restrict__ wt,      // [512 m][512 l]
                const u16* __restrict__ vnT,     // [B][512 c][512 l]
                const u16* __restrict__ headb,   // [B][512 m][64 d]
                const u16* __restrict__ projwT,  // [512 c][64 d]
                const float* __restrict__ x,
                const float* __restrict__ tbias,
                const float* __restrict__ projb,
                float* __restrict__ out) {
    __shared__ u16 As[2][128 * 64];              // 2 x 16 KiB
    __shared__ u16 Bs[2][128 * 64];              // 2 x 16 KiB  (total 64 KiB, 2 blk/CU)
    int lid = blockIdx.x;
    int p8 = lid & 7, rest = lid >> 3;
    int mi = rest & 3, pair = (rest >> 2) * 8 + p8;   // pair in [0,128)
    int b = pair >> 2, m0 = mi * 128, c0 = (pair & 3) * 128;
    int t = threadIdx.x, lane = t & 63, wid = t >> 6;
    int wm = (wid >> 1) * 64, wn = (wid & 1) * 64;
    int l15 = lane & 15, q16 = lane >> 4;
    f32x4 acc[4][4] = {};
    const u16* Ag = wt + (size_t)m0 * 512;
    const u16* Bg = vnT + ((size_t)b * H2 + c0) * 512;
    const u16* Hg = headb + ((size_t)b * LL + m0) * DA;
    const u16* Pg = projwT + (size_t)c0 * DA;

    // prologue: stage tile 0 (Toeplitz k0=0) into buf 0
    stage_pair(Ag, Bg, 512, 0, As[0], Bs[0], t);
    __syncthreads();                             // drains DMA

    // 9-tile pipeline: 8 Toeplitz K-slabs + proj as tile 8; stage-next ∥ MFMA-current
    for (int it = 0; it < 9; ++it) {
        int nx = it + 1;
        if (nx < 8)
            stage_pair(Ag, Bg, 512, nx * 64, As[nx & 1], Bs[nx & 1], t);
        else if (nx == 8)
            stage_pair(Hg, Pg, 64, 0, As[0], Bs[0], t);
        mfma_tile64(As[it & 1], Bs[it & 1], acc, wm, wn, l15, q16);
        __syncthreads();                         // next-buf ready; cur buf released
    }

    int rq = q16 * 4;
#pragma unroll
    for (int i = 0; i < 4; ++i) {
#pragma unroll
        for (int rr = 0; rr < 4; ++rr) {
            int m = m0 + wm + i * 16 + rq + rr;
            float tb = tbias[m];
            const float* xrow = x + ((size_t)b * LL + m) * HH;
            float* orow = out + ((size_t)b * LL + m) * H2;
#pragma unroll
            for (int j = 0; j < 4; ++j) {
                int c = c0 + wn + j * 16 + l15;
                float val = acc[i][j][rr] + tb + projb[c];
                orow[c] = xrow[c] * val;
            }
        }
    }
}

extern "C" void kernel_launch(void* const* d_in, const int* in_sizes, int n_in,
                              void* d_out, int out_size, void* d_ws, size_t ws_size,
                              hipStream_t stream) {
    (void)in_sizes; (void)n_in; (void)out_size; (void)ws_size;
    const float* x     = (const float*)d_in[0];
    const float* gamma = (const float*)d_in[1];
    const float* beta  = (const float*)d_in[2];
    const float* wv    = (const float*)d_in[3];
    const float* tb    = (const float*)d_in[4];
    const float* kqvw  = (const float*)d_in[5];
    const float* kqvb  = (const float*)d_in[6];
    const float* projw = (const float*)d_in[7];
    const float* projb = (const float*)d_in[8];
    float* out = (float*)d_out;

    u16* vnT_bf  = (u16*)d_ws;                          // 16 MB
    u16* qb      = vnT_bf + (size_t)NB * LL * H2;       // 2 MB
    u16* kb      = qb + (size_t)NB * LL * DA;           // 2 MB
    u16* vTb     = kb + (size_t)NB * LL * DA;           // 2 MB
    u16* head_bf = vTb + (size_t)NB * LL * DA;          // 2 MB
    u16* wt_bf   = head_bf + (size_t)NB * LL * DA;      // 512 KB
    u16* kqvwT   = wt_bf + 512 * 512;                   // 192 KB
    u16* projwT  = kqvwT + 192 * 512;                   // 64 KB

    prep_kernel <<<1536, 256, 0, stream>>>(wv, kqvw, projw, wt_bf, kqvwT, projwT);
    front_kernel<<<512, 256, 0, stream>>>(x, gamma, beta, kqvwT, kqvb,
                                          vnT_bf, qb, kb, vTb);
    attn_kernel <<<dim3(32, NB), 256, 0, stream>>>(qb, kb, vTb, head_bf);
    mix_kernel  <<<512, 256, 0, stream>>>(wt_bf, vnT_bf, head_bf, projwT,
                                          x, tb, projb, out);
}